// Round 2
// baseline (20054.585 us; speedup 1.0000x reference)
//
#include <hip/hip_runtime.h>
#include <hip/hip_bf16.h>

#define B_ 64
#define T_ 512
#define D_ 1024
#define H_ 1024

typedef __bf16 bf16x8 __attribute__((ext_vector_type(8)));
typedef float f32x4 __attribute__((ext_vector_type(4)));

static __device__ __forceinline__ unsigned short f2bf(float f) {
  union { float f; unsigned u; } v; v.f = f;
  unsigned u = v.u;
  unsigned r = (u + 0x7fffu + ((u >> 16) & 1u)) >> 16;
  return (unsigned short)r;
}

// xi = x @ Wi^T + bi  -> written to out[B,T,H] (overwritten later by h)
// M = B*T = 32768 rows, N = H = 1024 cols, K = D = 1024.
// bf16 MFMA 16x16x32, 128x128 tile, 4 waves (2x2), each wave 64x64 (4x4 frags).
__global__ __launch_bounds__(256) void xi_gemm(const float* __restrict__ x,
                                               const float* __restrict__ Wi,
                                               const float* __restrict__ bi,
                                               float* __restrict__ out) {
  __shared__ unsigned short As[128][40];  // 32 k + 8 pad
  __shared__ unsigned short Ws[128][40];
  const int tid = threadIdx.x;
  const int wave = tid >> 6;
  const int lane = tid & 63;
  const int wm = wave >> 1, wn = wave & 1;
  const int lr = lane & 15, lk = lane >> 4;
  const long row0 = (long)blockIdx.x * 128;
  const int col0 = (int)blockIdx.y * 128;

  f32x4 acc[4][4];
#pragma unroll
  for (int m = 0; m < 4; ++m)
#pragma unroll
    for (int n = 0; n < 4; ++n)
      acc[m][n] = (f32x4){0.f, 0.f, 0.f, 0.f};

  for (int kt = 0; kt < 32; ++kt) {
    __syncthreads();
    // stage: 128x32 fp32 -> bf16 LDS, A (x) and B (Wi, [N,K] row-major = B^T)
#pragma unroll
    for (int it = 0; it < 4; ++it) {
      int i = tid + it * 256;       // 0..1023 = 128 rows x 8 float4-chunks
      int row = i >> 3, c = i & 7;
      float4 va = *reinterpret_cast<const float4*>(
          &x[(row0 + row) * 1024 + kt * 32 + c * 4]);
      ushort4 ba = {f2bf(va.x), f2bf(va.y), f2bf(va.z), f2bf(va.w)};
      *reinterpret_cast<ushort4*>(&As[row][c * 4]) = ba;
      float4 vw = *reinterpret_cast<const float4*>(
          &Wi[(long)(col0 + row) * 1024 + kt * 32 + c * 4]);
      ushort4 bw = {f2bf(vw.x), f2bf(vw.y), f2bf(vw.z), f2bf(vw.w)};
      *reinterpret_cast<ushort4*>(&Ws[row][c * 4]) = bw;
    }
    __syncthreads();
    // A-frag: lane holds A[row=lr][k = lk*8 + 0..7]; B-frag same (Wi is [N,K])
    bf16x8 af[4], wf[4];
#pragma unroll
    for (int m = 0; m < 4; ++m)
      af[m] = *reinterpret_cast<const bf16x8*>(&As[wm * 64 + m * 16 + lr][lk * 8]);
#pragma unroll
    for (int n = 0; n < 4; ++n)
      wf[n] = *reinterpret_cast<const bf16x8*>(&Ws[wn * 64 + n * 16 + lr][lk * 8]);
#pragma unroll
    for (int m = 0; m < 4; ++m)
#pragma unroll
      for (int n = 0; n < 4; ++n)
        acc[m][n] = __builtin_amdgcn_mfma_f32_16x16x32_bf16(af[m], wf[n], acc[m][n], 0, 0, 0);
  }
  // epilogue: D mapping col = lane&15, row = (lane>>4)*4 + reg (m89-verified)
#pragma unroll
  for (int m = 0; m < 4; ++m) {
#pragma unroll
    for (int n = 0; n < 4; ++n) {
#pragma unroll
      for (int r = 0; r < 4; ++r) {
        long row = row0 + wm * 64 + m * 16 + lk * 4 + r;
        int col = col0 + wn * 64 + n * 16 + lr;
        out[row * 1024 + col] = acc[m][n][r] + bi[col];
      }
    }
  }
}

// One recurrence step: h_t = tanh(xi_t + Wh @ h_{t-1} + bh), all fp32.
// Grid 256 = 4 batch-groups x 64 j-groups; 256 threads = 16 b x 16 j,
// one output element per thread, 1024-long dot product.
// No LDS: Wh rows stream from L1/L2 (Wh = 4 MB, L2-resident after step 0);
// h_prev reads are uniform per 16-lane group (4 distinct 16B reqs / wave inst).
__global__ __launch_bounds__(256) void rnn_step(const float* __restrict__ Wh,
                                                const float* __restrict__ bh,
                                                float* __restrict__ out,
                                                int t) {
  const int bg = blockIdx.x & 3;
  const int jg = blockIdx.x >> 2;
  const int b = bg * 16 + (threadIdx.x >> 4);
  const int j = jg * 16 + (threadIdx.x & 15);
  float a0 = 0.f, a1 = 0.f, a2 = 0.f, a3 = 0.f;
  if (t > 0) {
    const float4* __restrict__ wr = reinterpret_cast<const float4*>(&Wh[(long)j * H_]);
    const float4* __restrict__ hr = reinterpret_cast<const float4*>(
        &out[((long)b * T_ + (t - 1)) * H_]);
    // 4 independent FMA chains (break the 4-cyc dependent-FMA latency)
#pragma unroll 8
    for (int kc = 0; kc < 256; ++kc) {
      float4 w = wr[kc];
      float4 h = hr[kc];
      a0 = fmaf(w.x, h.x, a0);
      a1 = fmaf(w.y, h.y, a1);
      a2 = fmaf(w.z, h.z, a2);
      a3 = fmaf(w.w, h.w, a3);
    }
  }
  const long oi = ((long)b * T_ + t) * H_ + j;
  float z = out[oi] + ((a0 + a1) + (a2 + a3)) + bh[j];
  out[oi] = tanhf(z);
}

extern "C" void kernel_launch(void* const* d_in, const int* in_sizes, int n_in,
                              void* d_out, int out_size, void* d_ws, size_t ws_size,
                              hipStream_t stream) {
  const float* x  = (const float*)d_in[0];
  const float* Wi = (const float*)d_in[1];
  const float* bi = (const float*)d_in[2];
  const float* Wh = (const float*)d_in[3];
  const float* bh = (const float*)d_in[4];
  float* out = (float*)d_out;

  hipLaunchKernelGGL(xi_gemm, dim3(256, 8), dim3(256), 0, stream, x, Wi, bi, out);
  for (int t = 0; t < T_; ++t)
    hipLaunchKernelGGL(rnn_step, dim3(256), dim3(256), 0, stream, Wh, bh, out, t);
}

// Round 5
// 10269.942 us; speedup vs baseline: 1.9527x; 1.9527x over previous
//
#include <hip/hip_runtime.h>
#include <hip/hip_bf16.h>
#include <hip/hip_cooperative_groups.h>

namespace cg = cooperative_groups;

#define B_ 64
#define T_ 512
#define D_ 1024
#define H_ 1024
#define NB 64  // persistent blocks: 1 per 16 output columns

typedef __bf16 bf16x8 __attribute__((ext_vector_type(8)));
typedef float f32x4 __attribute__((ext_vector_type(4)));

static __device__ __forceinline__ unsigned short f2bf(float f) {
  union { float f; unsigned u; } v; v.f = f;
  unsigned u = v.u;
  unsigned r = (u + 0x7fffu + ((u >> 16) & 1u)) >> 16;
  return (unsigned short)r;
}
static __device__ __forceinline__ float bf2f(unsigned short b) {
  union { unsigned u; float f; } v; v.u = ((unsigned)b) << 16;
  return v.f;
}

// ---------------------------------------------------------------------------
// xi = x @ Wi^T + bi -> out[B,T,H]  (validated round 2; overwritten by h later)
// ---------------------------------------------------------------------------
__global__ __launch_bounds__(256) void xi_gemm(const float* __restrict__ x,
                                               const float* __restrict__ Wi,
                                               const float* __restrict__ bi,
                                               float* __restrict__ out) {
  __shared__ __align__(16) unsigned short As[128][40];
  __shared__ __align__(16) unsigned short Ws[128][40];
  const int tid = threadIdx.x;
  const int wave = tid >> 6;
  const int lane = tid & 63;
  const int wm = wave >> 1, wn = wave & 1;
  const int lr = lane & 15, lk = lane >> 4;
  const long row0 = (long)blockIdx.x * 128;
  const int col0 = (int)blockIdx.y * 128;

  f32x4 acc[4][4];
#pragma unroll
  for (int m = 0; m < 4; ++m)
#pragma unroll
    for (int n = 0; n < 4; ++n)
      acc[m][n] = (f32x4){0.f, 0.f, 0.f, 0.f};

  for (int kt = 0; kt < 32; ++kt) {
    __syncthreads();
#pragma unroll
    for (int it = 0; it < 4; ++it) {
      int i = tid + it * 256;
      int row = i >> 3, c = i & 7;
      float4 va = *reinterpret_cast<const float4*>(
          &x[(row0 + row) * 1024 + kt * 32 + c * 4]);
      ushort4 ba = {f2bf(va.x), f2bf(va.y), f2bf(va.z), f2bf(va.w)};
      *reinterpret_cast<ushort4*>(&As[row][c * 4]) = ba;
      float4 vw = *reinterpret_cast<const float4*>(
          &Wi[(long)(col0 + row) * 1024 + kt * 32 + c * 4]);
      ushort4 bw = {f2bf(vw.x), f2bf(vw.y), f2bf(vw.z), f2bf(vw.w)};
      *reinterpret_cast<ushort4*>(&Ws[row][c * 4]) = bw;
    }
    __syncthreads();
    bf16x8 af[4], wf[4];
#pragma unroll
    for (int m = 0; m < 4; ++m)
      af[m] = *reinterpret_cast<const bf16x8*>(&As[wm * 64 + m * 16 + lr][lk * 8]);
#pragma unroll
    for (int n = 0; n < 4; ++n)
      wf[n] = *reinterpret_cast<const bf16x8*>(&Ws[wn * 64 + n * 16 + lr][lk * 8]);
#pragma unroll
    for (int m = 0; m < 4; ++m)
#pragma unroll
      for (int n = 0; n < 4; ++n)
        acc[m][n] = __builtin_amdgcn_mfma_f32_16x16x32_bf16(af[m], wf[n], acc[m][n], 0, 0, 0);
  }
#pragma unroll
  for (int m = 0; m < 4; ++m) {
#pragma unroll
    for (int n = 0; n < 4; ++n) {
#pragma unroll
      for (int r = 0; r < 4; ++r) {
        long row = row0 + wm * 64 + m * 16 + lk * 4 + r;
        int col = col0 + wn * 64 + n * 16 + lr;
        out[row * 1024 + col] = acc[m][n][r] + bi[col];
      }
    }
  }
}

// ---------------------------------------------------------------------------
// Persistent recurrence (COOPERATIVE): h_t = tanh(xi_t + Wh @ h_{t-1} + bh).
// 64 blocks x 256 thr. Block owns 16 j-columns; Wh slice LDS-resident (bf16).
// h carried as bf16 hi+lo split (2 MFMA passes -> ~fp32-accurate h operand),
// double-buffered in d_ws; grid.sync() once per step (sanctioned primitive,
// handles cross-XCD visibility; no hand-rolled spin). Step t writes
// out[:,t,:] + hbuf[t&1], reads out[:,t,:] (xi) + hbuf[(t-1)&1]:
// RAW guarded by sync, WAR by arrival order.
// ---------------------------------------------------------------------------
__global__ __launch_bounds__(256) void rnn_persist(const float* __restrict__ Wh,
                                                   const float* __restrict__ bh,
                                                   float* __restrict__ out,
                                                   unsigned short* __restrict__ hhi,
                                                   unsigned short* __restrict__ hlo) {
  cg::grid_group grid = cg::this_grid();
  __shared__ __align__(16) unsigned short Whs[16][1032];  // +8 pad
  const int tid = threadIdx.x;
  const int wave = tid >> 6, lane = tid & 63;
  const int lr = lane & 15, lk = lane >> 4;
  const int j0 = blockIdx.x * 16;

  // stage Wh rows j0..j0+15 -> LDS bf16 (once)
#pragma unroll
  for (int it = 0; it < 16; ++it) {
    int i = tid + it * 256;      // 0..4095 = 16 rows x 256 float4 chunks
    int row = i >> 8, c = i & 255;
    float4 v = *reinterpret_cast<const float4*>(&Wh[(long)(j0 + row) * 1024 + c * 4]);
    ushort4 b4 = {f2bf(v.x), f2bf(v.y), f2bf(v.z), f2bf(v.w)};
    *reinterpret_cast<ushort4*>(&Whs[row][c * 4]) = b4;
  }
  const float bhv = bh[j0 + lr];
  __syncthreads();

  const int brow = wave * 16;                    // this wave's batch-row tile
  const unsigned short* wbl = &Whs[lr][lk * 8];  // B-frag base (col j0+lr)

  for (int t = 0; t < T_; ++t) {
    if (t > 0) grid.sync();

    f32x4 a00 = {0,0,0,0}, a01 = {0,0,0,0}, a10 = {0,0,0,0}, a11 = {0,0,0,0};
    if (t > 0) {
      const size_t hb = (size_t)((t - 1) & 1) * (64 * 1024);
      const unsigned short* hbl = hhi + hb + (size_t)(brow + lr) * 1024 + lk * 8;
      const unsigned short* lbl = hlo + hb + (size_t)(brow + lr) * 1024 + lk * 8;
      // 4 independent MFMA chains (hi/lo x two K-halves), 16 deep each
#pragma unroll 4
      for (int ks = 0; ks < 16; ++ks) {
        bf16x8 ah0 = *reinterpret_cast<const bf16x8*>(hbl + ks * 32);
        bf16x8 al0 = *reinterpret_cast<const bf16x8*>(lbl + ks * 32);
        bf16x8 ah1 = *reinterpret_cast<const bf16x8*>(hbl + (ks + 16) * 32);
        bf16x8 al1 = *reinterpret_cast<const bf16x8*>(lbl + (ks + 16) * 32);
        bf16x8 wf0 = *reinterpret_cast<const bf16x8*>(wbl + ks * 32);
        bf16x8 wf1 = *reinterpret_cast<const bf16x8*>(wbl + (ks + 16) * 32);
        a00 = __builtin_amdgcn_mfma_f32_16x16x32_bf16(ah0, wf0, a00, 0, 0, 0);
        a01 = __builtin_amdgcn_mfma_f32_16x16x32_bf16(al0, wf0, a01, 0, 0, 0);
        a10 = __builtin_amdgcn_mfma_f32_16x16x32_bf16(ah1, wf1, a10, 0, 0, 0);
        a11 = __builtin_amdgcn_mfma_f32_16x16x32_bf16(al1, wf1, a11, 0, 0, 0);
      }
    }
    f32x4 acc = (a00 + a01) + (a10 + a11);

    // epilogue: lane owns col j0+lr, rows brow + lk*4 + r (m89 D-layout)
    unsigned short* whi = hhi + (size_t)(t & 1) * (64 * 1024);
    unsigned short* wlo = hlo + (size_t)(t & 1) * (64 * 1024);
    const int jcol = j0 + lr;
#pragma unroll
    for (int r = 0; r < 4; ++r) {
      int b = brow + lk * 4 + r;
      size_t oi = ((size_t)b * T_ + t) * H_ + jcol;
      float z = out[oi] + acc[r] + bhv;
      float h = tanhf(z);
      out[oi] = h;
      unsigned short hi16 = f2bf(h);
      float lof = h - bf2f(hi16);
      whi[(size_t)b * 1024 + jcol] = hi16;
      wlo[(size_t)b * 1024 + jcol] = f2bf(lof);
    }
  }
}

// ---------------------------------------------------------------------------
// Fallback step kernel (round-2 validated): used only if ws_size is too small.
// ---------------------------------------------------------------------------
__global__ __launch_bounds__(256) void rnn_step(const float* __restrict__ Wh,
                                                const float* __restrict__ bh,
                                                float* __restrict__ out,
                                                int t) {
  const int bg = blockIdx.x & 3;
  const int jg = blockIdx.x >> 2;
  const int b = bg * 16 + (threadIdx.x >> 4);
  const int j = jg * 16 + (threadIdx.x & 15);
  float a0 = 0.f, a1 = 0.f, a2 = 0.f, a3 = 0.f;
  if (t > 0) {
    const float4* __restrict__ wr = reinterpret_cast<const float4*>(&Wh[(long)j * H_]);
    const float4* __restrict__ hr = reinterpret_cast<const float4*>(
        &out[((long)b * T_ + (t - 1)) * H_]);
#pragma unroll 8
    for (int kc = 0; kc < 256; ++kc) {
      float4 w = wr[kc];
      float4 h = hr[kc];
      a0 = fmaf(w.x, h.x, a0);
      a1 = fmaf(w.y, h.y, a1);
      a2 = fmaf(w.z, h.z, a2);
      a3 = fmaf(w.w, h.w, a3);
    }
  }
  const long oi = ((long)b * T_ + t) * H_ + j;
  float z = out[oi] + ((a0 + a1) + (a2 + a3)) + bh[j];
  out[oi] = tanhf(z);
}

extern "C" void kernel_launch(void* const* d_in, const int* in_sizes, int n_in,
                              void* d_out, int out_size, void* d_ws, size_t ws_size,
                              hipStream_t stream) {
  const float* x  = (const float*)d_in[0];
  const float* Wi = (const float*)d_in[1];
  const float* bi = (const float*)d_in[2];
  const float* Wh = (const float*)d_in[3];
  const float* bh = (const float*)d_in[4];
  float* out = (float*)d_out;

  hipLaunchKernelGGL(xi_gemm, dim3(256, 8), dim3(256), 0, stream, x, Wi, bi, out);

  // ws layout: hi[2][64][1024] ushort | lo[2][64][1024] ushort  (512 KB)
  const size_t need = (size_t)4 * 64 * 1024 * sizeof(unsigned short);
  if (ws_size >= need) {
    unsigned short* hhi = (unsigned short*)d_ws;
    unsigned short* hlo = hhi + 2 * 64 * 1024;
    const float* Wh_ = Wh; const float* bh_ = bh; float* out_ = out;
    void* args[] = {(void*)&Wh_, (void*)&bh_, (void*)&out_, (void*)&hhi, (void*)&hlo};
    hipLaunchCooperativeKernel((void*)rnn_persist, dim3(NB), dim3(256),
                               args, 0, stream);
  } else {
    // deterministic fallback (validated round 2)
    for (int t = 0; t < T_; ++t)
      hipLaunchKernelGGL(rnn_step, dim3(256), dim3(256), 0, stream, Wh, bh, out, t);
  }
}

// Round 6
// 10107.326 us; speedup vs baseline: 1.9842x; 1.0161x over previous
//
#include <hip/hip_runtime.h>
#include <hip/hip_bf16.h>

#define B_ 64
#define T_ 512
#define D_ 1024
#define H_ 1024
#define NB 64  // persistent blocks: 1 per 16 output columns

typedef __bf16 bf16x8 __attribute__((ext_vector_type(8)));
typedef float f32x4 __attribute__((ext_vector_type(4)));

static __device__ __forceinline__ unsigned short f2bf(float f) {
  union { float f; unsigned u; } v; v.f = f;
  unsigned u = v.u;
  unsigned r = (u + 0x7fffu + ((u >> 16) & 1u)) >> 16;
  return (unsigned short)r;
}
static __device__ __forceinline__ float bf2f(unsigned short b) {
  union { unsigned u; float f; } v; v.u = ((unsigned)b) << 16;
  return v.f;
}

// ---------------------------------------------------------------------------
// xi = x @ Wi^T + bi -> out[B,T,H]  (validated rounds 2/5)
// ---------------------------------------------------------------------------
__global__ __launch_bounds__(256) void xi_gemm(const float* __restrict__ x,
                                               const float* __restrict__ Wi,
                                               const float* __restrict__ bi,
                                               float* __restrict__ out) {
  __shared__ __align__(16) unsigned short As[128][40];
  __shared__ __align__(16) unsigned short Ws[128][40];
  const int tid = threadIdx.x;
  const int wave = tid >> 6;
  const int lane = tid & 63;
  const int wm = wave >> 1, wn = wave & 1;
  const int lr = lane & 15, lk = lane >> 4;
  const long row0 = (long)blockIdx.x * 128;
  const int col0 = (int)blockIdx.y * 128;

  f32x4 acc[4][4];
#pragma unroll
  for (int m = 0; m < 4; ++m)
#pragma unroll
    for (int n = 0; n < 4; ++n)
      acc[m][n] = (f32x4){0.f, 0.f, 0.f, 0.f};

  for (int kt = 0; kt < 32; ++kt) {
    __syncthreads();
#pragma unroll
    for (int it = 0; it < 4; ++it) {
      int i = tid + it * 256;
      int row = i >> 3, c = i & 7;
      float4 va = *reinterpret_cast<const float4*>(
          &x[(row0 + row) * 1024 + kt * 32 + c * 4]);
      ushort4 ba = {f2bf(va.x), f2bf(va.y), f2bf(va.z), f2bf(va.w)};
      *reinterpret_cast<ushort4*>(&As[row][c * 4]) = ba;
      float4 vw = *reinterpret_cast<const float4*>(
          &Wi[(long)(col0 + row) * 1024 + kt * 32 + c * 4]);
      ushort4 bw = {f2bf(vw.x), f2bf(vw.y), f2bf(vw.z), f2bf(vw.w)};
      *reinterpret_cast<ushort4*>(&Ws[row][c * 4]) = bw;
    }
    __syncthreads();
    bf16x8 af[4], wf[4];
#pragma unroll
    for (int m = 0; m < 4; ++m)
      af[m] = *reinterpret_cast<const bf16x8*>(&As[wm * 64 + m * 16 + lr][lk * 8]);
#pragma unroll
    for (int n = 0; n < 4; ++n)
      wf[n] = *reinterpret_cast<const bf16x8*>(&Ws[wn * 64 + n * 16 + lr][lk * 8]);
#pragma unroll
    for (int m = 0; m < 4; ++m)
#pragma unroll
      for (int n = 0; n < 4; ++n)
        acc[m][n] = __builtin_amdgcn_mfma_f32_16x16x32_bf16(af[m], wf[n], acc[m][n], 0, 0, 0);
  }
#pragma unroll
  for (int m = 0; m < 4; ++m) {
#pragma unroll
    for (int n = 0; n < 4; ++n) {
#pragma unroll
      for (int r = 0; r < 4; ++r) {
        long row = row0 + wm * 64 + m * 16 + lk * 4 + r;
        int col = col0 + wn * 64 + n * 16 + lr;
        out[row * 1024 + col] = acc[m][n][r] + bi[col];
      }
    }
  }
}

// ---------------------------------------------------------------------------
// Persistent recurrence, custom LLC barrier (replaces 20 us/step grid.sync).
// h state lives in d_ws as packed bf16 hi/lo col-pairs, moved ONLY via
// agent-scope relaxed atomics (execute at the coherence point, bypassing the
// non-coherent per-XCD L2s). Barrier: monotonic counter; __syncthreads drains
// vmcnt(0) before s_barrier [HIP-compiler, m97], so all h-stores are at LLC
// before tid0's fetch_add; spin is capped (wrong-answer instead of wedge).
// Layout (64-bit view hq): hi[2][64][256] ull | lo[2][64][256] ull (512 KB).
// 32-bit view s32: hi word idx = p*32768 + b*512 + jp (jp = col-pair).
// ---------------------------------------------------------------------------
__global__ __launch_bounds__(256) void rnn_persist(const float* __restrict__ Wh,
                                                   const float* __restrict__ bh,
                                                   float* __restrict__ out,
                                                   unsigned* __restrict__ ctr,
                                                   unsigned long long* __restrict__ hq) {
  __shared__ __align__(16) unsigned short Whs[16][1032];  // +8 pad
  const int tid = threadIdx.x;
  const int wave = tid >> 6, lane = tid & 63;
  const int lr = lane & 15, lk = lane >> 4;
  const int j0 = blockIdx.x * 16;

  // stage Wh rows j0..j0+15 -> LDS bf16 (once)
#pragma unroll
  for (int it = 0; it < 16; ++it) {
    int i = tid + it * 256;      // 16 rows x 256 float4 chunks
    int row = i >> 8, c = i & 255;
    float4 v = *reinterpret_cast<const float4*>(&Wh[(long)(j0 + row) * 1024 + c * 4]);
    ushort4 b4 = {f2bf(v.x), f2bf(v.y), f2bf(v.z), f2bf(v.w)};
    *reinterpret_cast<ushort4*>(&Whs[row][c * 4]) = b4;
  }
  const float bhv = bh[j0 + lr];
  __syncthreads();

  const int brow = wave * 16;                    // this wave's batch-row tile
  const unsigned short* wbl = &Whs[lr][lk * 8];  // B-frag base (col j0+lr)
  unsigned* s32 = reinterpret_cast<unsigned*>(hq);
  const int jp = (j0 >> 1) + (lr >> 1);          // col-pair index (shared by lane pairs)

  for (int t = 0; t < T_; ++t) {
    if (t > 0) {
      __syncthreads();  // drains vmcnt(0) -> this block's h-stores are at LLC
      if (tid == 0) {
        __hip_atomic_fetch_add(ctr, 1u, __ATOMIC_RELAXED, __HIP_MEMORY_SCOPE_AGENT);
        const unsigned tgt = (unsigned)NB * (unsigned)t;
        unsigned spin = 0;
        while (__hip_atomic_load(ctr, __ATOMIC_RELAXED, __HIP_MEMORY_SCOPE_AGENT) < tgt) {
          __builtin_amdgcn_s_sleep(1);
          if (++spin > 300000u) break;  // safety valve: fail loud, don't wedge
        }
      }
      __syncthreads();
    }

    f32x4 a00 = {0,0,0,0}, a01 = {0,0,0,0}, a10 = {0,0,0,0}, a11 = {0,0,0,0};
    if (t > 0) {
      const size_t pb = (size_t)((t - 1) & 1) * 16384;   // parity base (ull units)
      const unsigned long long* hb = hq + pb + (size_t)(brow + lr) * 256;
      const unsigned long long* lb = hb + 32768;          // lo array offset (ull)
      // 4 independent MFMA chains (hi/lo x two K-halves), 16 deep each
#pragma unroll 4
      for (int ks = 0; ks < 16; ++ks) {
        const int q0 = ks * 8 + lk * 2;
        union { unsigned long long q[2]; bf16x8 v; } uh0, ul0, uh1, ul1;
        uh0.q[0] = __hip_atomic_load(hb + q0,       __ATOMIC_RELAXED, __HIP_MEMORY_SCOPE_AGENT);
        uh0.q[1] = __hip_atomic_load(hb + q0 + 1,   __ATOMIC_RELAXED, __HIP_MEMORY_SCOPE_AGENT);
        ul0.q[0] = __hip_atomic_load(lb + q0,       __ATOMIC_RELAXED, __HIP_MEMORY_SCOPE_AGENT);
        ul0.q[1] = __hip_atomic_load(lb + q0 + 1,   __ATOMIC_RELAXED, __HIP_MEMORY_SCOPE_AGENT);
        uh1.q[0] = __hip_atomic_load(hb + q0 + 128, __ATOMIC_RELAXED, __HIP_MEMORY_SCOPE_AGENT);
        uh1.q[1] = __hip_atomic_load(hb + q0 + 129, __ATOMIC_RELAXED, __HIP_MEMORY_SCOPE_AGENT);
        ul1.q[0] = __hip_atomic_load(lb + q0 + 128, __ATOMIC_RELAXED, __HIP_MEMORY_SCOPE_AGENT);
        ul1.q[1] = __hip_atomic_load(lb + q0 + 129, __ATOMIC_RELAXED, __HIP_MEMORY_SCOPE_AGENT);
        bf16x8 wf0 = *reinterpret_cast<const bf16x8*>(wbl + ks * 32);
        bf16x8 wf1 = *reinterpret_cast<const bf16x8*>(wbl + (ks + 16) * 32);
        a00 = __builtin_amdgcn_mfma_f32_16x16x32_bf16(uh0.v, wf0, a00, 0, 0, 0);
        a01 = __builtin_amdgcn_mfma_f32_16x16x32_bf16(ul0.v, wf0, a01, 0, 0, 0);
        a10 = __builtin_amdgcn_mfma_f32_16x16x32_bf16(uh1.v, wf1, a10, 0, 0, 0);
        a11 = __builtin_amdgcn_mfma_f32_16x16x32_bf16(ul1.v, wf1, a11, 0, 0, 0);
      }
    }
    f32x4 acc = (a00 + a01) + (a10 + a11);

    // epilogue: lane owns col j0+lr, rows brow + lk*4 + r (m89 D-layout).
    // Lane pairs (lr^1) exchange via shfl to pack bf16 col-pairs into u32;
    // even lane stores hi-pair, odd lane stores lo-pair (agent-relaxed -> LLC).
    const unsigned pw = (unsigned)(t & 1) * 32768u;
    const int jcol = j0 + lr;
#pragma unroll
    for (int r = 0; r < 4; ++r) {
      int b = brow + lk * 4 + r;
      size_t oi = ((size_t)b * T_ + t) * H_ + jcol;
      float z = out[oi] + acc[r] + bhv;
      float h = tanhf(z);
      out[oi] = h;
      unsigned hi_u = f2bf(h);
      unsigned lo_u = f2bf(h - bf2f((unsigned short)hi_u));
      unsigned o_hi = (unsigned)__shfl_xor((int)hi_u, 1, 64);
      unsigned o_lo = (unsigned)__shfl_xor((int)lo_u, 1, 64);
      unsigned widx = pw + (unsigned)b * 512u + (unsigned)jp;
      if ((lr & 1) == 0) {
        __hip_atomic_store(&s32[widx], hi_u | (o_hi << 16),
                           __ATOMIC_RELAXED, __HIP_MEMORY_SCOPE_AGENT);
      } else {
        __hip_atomic_store(&s32[65536u + widx], o_lo | (lo_u << 16),
                           __ATOMIC_RELAXED, __HIP_MEMORY_SCOPE_AGENT);
      }
    }
  }
}

// ---------------------------------------------------------------------------
// Fallback step kernel (round-2 validated): used only if ws_size is too small.
// ---------------------------------------------------------------------------
__global__ __launch_bounds__(256) void rnn_step(const float* __restrict__ Wh,
                                                const float* __restrict__ bh,
                                                float* __restrict__ out,
                                                int t) {
  const int bg = blockIdx.x & 3;
  const int jg = blockIdx.x >> 2;
  const int b = bg * 16 + (threadIdx.x >> 4);
  const int j = jg * 16 + (threadIdx.x & 15);
  float a0 = 0.f, a1 = 0.f, a2 = 0.f, a3 = 0.f;
  if (t > 0) {
    const float4* __restrict__ wr = reinterpret_cast<const float4*>(&Wh[(long)j * H_]);
    const float4* __restrict__ hr = reinterpret_cast<const float4*>(
        &out[((long)b * T_ + (t - 1)) * H_]);
#pragma unroll 8
    for (int kc = 0; kc < 256; ++kc) {
      float4 w = wr[kc];
      float4 h = hr[kc];
      a0 = fmaf(w.x, h.x, a0);
      a1 = fmaf(w.y, h.y, a1);
      a2 = fmaf(w.z, h.z, a2);
      a3 = fmaf(w.w, h.w, a3);
    }
  }
  const long oi = ((long)b * T_ + t) * H_ + j;
  float z = out[oi] + ((a0 + a1) + (a2 + a3)) + bh[j];
  out[oi] = tanhf(z);
}

extern "C" void kernel_launch(void* const* d_in, const int* in_sizes, int n_in,
                              void* d_out, int out_size, void* d_ws, size_t ws_size,
                              hipStream_t stream) {
  const float* x  = (const float*)d_in[0];
  const float* Wi = (const float*)d_in[1];
  const float* bi = (const float*)d_in[2];
  const float* Wh = (const float*)d_in[3];
  const float* bh = (const float*)d_in[4];
  float* out = (float*)d_out;

  hipLaunchKernelGGL(xi_gemm, dim3(256, 8), dim3(256), 0, stream, x, Wi, bi, out);

  // ws: [0,256) ctr | hi[2][64][256] ull | lo[2][64][256] ull  (256 B + 512 KB)
  const size_t need = 256 + (size_t)4 * 64 * 1024 * sizeof(unsigned short);
  if (ws_size >= need) {
    unsigned* ctr = (unsigned*)d_ws;
    unsigned long long* hq = (unsigned long long*)((char*)d_ws + 256);
    hipMemsetAsync(d_ws, 0, 256, stream);  // reset barrier counter (capture-safe)
    const float* Wh_ = Wh; const float* bh_ = bh; float* out_ = out;
    void* args[] = {(void*)&Wh_, (void*)&bh_, (void*)&out_, (void*)&ctr, (void*)&hq};
    hipLaunchCooperativeKernel((void*)rnn_persist, dim3(NB), dim3(256),
                               args, 0, stream);
  } else {
    // deterministic fallback (validated round 2)
    for (int t = 0; t < T_; ++t)
      hipLaunchKernelGGL(rnn_step, dim3(256), dim3(256), 0, stream, Wh, bh, out, t);
  }
}

// Round 7
// 7893.221 us; speedup vs baseline: 2.5407x; 1.2805x over previous
//
#include <hip/hip_runtime.h>
#include <hip/hip_bf16.h>

#define B_ 64
#define T_ 512
#define D_ 1024
#define H_ 1024
#define NB 64  // persistent blocks: 1 per 16 output columns

typedef __bf16 bf16x8 __attribute__((ext_vector_type(8)));
typedef float f32x4 __attribute__((ext_vector_type(4)));

static __device__ __forceinline__ unsigned short f2bf(float f) {
  union { float f; unsigned u; } v; v.f = f;
  unsigned u = v.u;
  unsigned r = (u + 0x7fffu + ((u >> 16) & 1u)) >> 16;
  return (unsigned short)r;
}
static __device__ __forceinline__ float bf2f(unsigned short b) {
  union { unsigned u; float f; } v; v.u = ((unsigned)b) << 16;
  return v.f;
}

// ---------------------------------------------------------------------------
// xi = x @ Wi^T + bi -> out[B,T,H]  (validated rounds 2/5/6)
// ---------------------------------------------------------------------------
__global__ __launch_bounds__(256) void xi_gemm(const float* __restrict__ x,
                                               const float* __restrict__ Wi,
                                               const float* __restrict__ bi,
                                               float* __restrict__ out) {
  __shared__ __align__(16) unsigned short As[128][40];
  __shared__ __align__(16) unsigned short Ws[128][40];
  const int tid = threadIdx.x;
  const int wave = tid >> 6;
  const int lane = tid & 63;
  const int wm = wave >> 1, wn = wave & 1;
  const int lr = lane & 15, lk = lane >> 4;
  const long row0 = (long)blockIdx.x * 128;
  const int col0 = (int)blockIdx.y * 128;

  f32x4 acc[4][4];
#pragma unroll
  for (int m = 0; m < 4; ++m)
#pragma unroll
    for (int n = 0; n < 4; ++n)
      acc[m][n] = (f32x4){0.f, 0.f, 0.f, 0.f};

  for (int kt = 0; kt < 32; ++kt) {
    __syncthreads();
#pragma unroll
    for (int it = 0; it < 4; ++it) {
      int i = tid + it * 256;
      int row = i >> 3, c = i & 7;
      float4 va = *reinterpret_cast<const float4*>(
          &x[(row0 + row) * 1024 + kt * 32 + c * 4]);
      ushort4 ba = {f2bf(va.x), f2bf(va.y), f2bf(va.z), f2bf(va.w)};
      *reinterpret_cast<ushort4*>(&As[row][c * 4]) = ba;
      float4 vw = *reinterpret_cast<const float4*>(
          &Wi[(long)(col0 + row) * 1024 + kt * 32 + c * 4]);
      ushort4 bw = {f2bf(vw.x), f2bf(vw.y), f2bf(vw.z), f2bf(vw.w)};
      *reinterpret_cast<ushort4*>(&Ws[row][c * 4]) = bw;
    }
    __syncthreads();
    bf16x8 af[4], wf[4];
#pragma unroll
    for (int m = 0; m < 4; ++m)
      af[m] = *reinterpret_cast<const bf16x8*>(&As[wm * 64 + m * 16 + lr][lk * 8]);
#pragma unroll
    for (int n = 0; n < 4; ++n)
      wf[n] = *reinterpret_cast<const bf16x8*>(&Ws[wn * 64 + n * 16 + lr][lk * 8]);
#pragma unroll
    for (int m = 0; m < 4; ++m)
#pragma unroll
      for (int n = 0; n < 4; ++n)
        acc[m][n] = __builtin_amdgcn_mfma_f32_16x16x32_bf16(af[m], wf[n], acc[m][n], 0, 0, 0);
  }
#pragma unroll
  for (int m = 0; m < 4; ++m) {
#pragma unroll
    for (int n = 0; n < 4; ++n) {
#pragma unroll
      for (int r = 0; r < 4; ++r) {
        long row = row0 + wm * 64 + m * 16 + lk * 4 + r;
        int col = col0 + wn * 64 + n * 16 + lr;
        out[row * 1024 + col] = acc[m][n][r] + bi[col];
      }
    }
  }
}

// ---------------------------------------------------------------------------
// Persistent recurrence, v3: plain CACHED h exchange + explicit fences.
// h hi/lo bf16 state in d_ws, accessed with ordinary (L1/L2-cached, wide,
// coalesced) loads/stores. Cross-XCD visibility: ONE __threadfence() per
// block per side, tid0 only:
//   stores -> __syncthreads (all waves vmcnt-drained to L2 [m97]) ->
//   tid0 { threadfence (wbl2: dirty lines -> LLC); arrive; spin;
//          threadfence (inv: L1+L2 stale lines dropped) } -> __syncthreads.
// All 4 waves share one CU/L1, so tid0's inv covers the block.
// Barrier: round-6-validated monotonic counter, relaxed agent atomics,
// capped spin (fail-loud, no wedge). Cooperative launch for co-residency.
// ws ushort layout: hi[p][b][j] @ p*65536+b*1024+j ; lo = +131072.
// ---------------------------------------------------------------------------
__global__ __launch_bounds__(256) void rnn_persist(const float* __restrict__ Wh,
                                                   const float* __restrict__ bh,
                                                   float* __restrict__ out,
                                                   unsigned* __restrict__ ctr,
                                                   unsigned short* __restrict__ hs) {
  __shared__ __align__(16) unsigned short Whs[16][1032];  // +8 pad
  const int tid = threadIdx.x;
  const int wave = tid >> 6, lane = tid & 63;
  const int lr = lane & 15, lk = lane >> 4;
  const int j0 = blockIdx.x * 16;

  // stage Wh rows j0..j0+15 -> LDS bf16 (once)
#pragma unroll
  for (int it = 0; it < 16; ++it) {
    int i = tid + it * 256;      // 16 rows x 256 float4 chunks
    int row = i >> 8, c = i & 255;
    float4 v = *reinterpret_cast<const float4*>(&Wh[(long)(j0 + row) * 1024 + c * 4]);
    ushort4 b4 = {f2bf(v.x), f2bf(v.y), f2bf(v.z), f2bf(v.w)};
    *reinterpret_cast<ushort4*>(&Whs[row][c * 4]) = b4;
  }
  const float bhv = bh[j0 + lr];
  __syncthreads();

  const int brow = wave * 16;                    // this wave's batch-row tile
  const unsigned short* wbl = &Whs[lr][lk * 8];  // B-frag base (col j0+lr)
  unsigned* hw = reinterpret_cast<unsigned*>(hs);
  const int jp = (j0 >> 1) + (lr >> 1);          // col-pair index

  for (int t = 0; t < T_; ++t) {
    if (t > 0) {
      __syncthreads();  // all waves' stores drained to L2 (vmcnt(0) pre-barrier)
      if (tid == 0) {
        __threadfence();  // release: writeback this XCD's dirty lines to LLC
        __hip_atomic_fetch_add(ctr, 1u, __ATOMIC_RELAXED, __HIP_MEMORY_SCOPE_AGENT);
        const unsigned tgt = (unsigned)NB * (unsigned)t;
        unsigned spin = 0;
        while (__hip_atomic_load(ctr, __ATOMIC_RELAXED, __HIP_MEMORY_SCOPE_AGENT) < tgt) {
          __builtin_amdgcn_s_sleep(1);
          if (++spin > 300000u) break;  // safety valve: fail loud, don't wedge
        }
        __threadfence();  // acquire: invalidate L1/L2 so plain loads see LLC
      }
      __syncthreads();    // other waves wait for tid0's inv
    }

    f32x4 a00 = {0,0,0,0}, a01 = {0,0,0,0}, a10 = {0,0,0,0}, a11 = {0,0,0,0};
    if (t > 0) {
      const size_t pb = (size_t)((t - 1) & 1) * 65536;   // parity base (ushort)
      const unsigned short* hbl = hs + pb + (size_t)(brow + lr) * 1024 + lk * 8;
      const unsigned short* lbl = hbl + 131072;           // lo array offset
      // 4 independent MFMA chains (hi/lo x two K-halves), 16 deep each
#pragma unroll 4
      for (int ks = 0; ks < 16; ++ks) {
        bf16x8 ah0 = *reinterpret_cast<const bf16x8*>(hbl + ks * 32);
        bf16x8 al0 = *reinterpret_cast<const bf16x8*>(lbl + ks * 32);
        bf16x8 ah1 = *reinterpret_cast<const bf16x8*>(hbl + (ks + 16) * 32);
        bf16x8 al1 = *reinterpret_cast<const bf16x8*>(lbl + (ks + 16) * 32);
        bf16x8 wf0 = *reinterpret_cast<const bf16x8*>(wbl + ks * 32);
        bf16x8 wf1 = *reinterpret_cast<const bf16x8*>(wbl + (ks + 16) * 32);
        a00 = __builtin_amdgcn_mfma_f32_16x16x32_bf16(ah0, wf0, a00, 0, 0, 0);
        a01 = __builtin_amdgcn_mfma_f32_16x16x32_bf16(al0, wf0, a01, 0, 0, 0);
        a10 = __builtin_amdgcn_mfma_f32_16x16x32_bf16(ah1, wf1, a10, 0, 0, 0);
        a11 = __builtin_amdgcn_mfma_f32_16x16x32_bf16(al1, wf1, a11, 0, 0, 0);
      }
    }
    f32x4 acc = (a00 + a01) + (a10 + a11);

    // epilogue: lane owns col j0+lr, rows brow + lk*4 + r (m89 D-layout).
    // Lane pairs exchange via shfl; even lane stores packed hi col-pair,
    // odd lane stores packed lo col-pair (plain cached u32 stores).
    const unsigned pw = (unsigned)(t & 1) * 32768u;      // parity base (u32)
    const int jcol = j0 + lr;
#pragma unroll
    for (int r = 0; r < 4; ++r) {
      int b = brow + lk * 4 + r;
      size_t oi = ((size_t)b * T_ + t) * H_ + jcol;
      float z = out[oi] + acc[r] + bhv;
      float h = tanhf(z);
      out[oi] = h;
      unsigned hi_u = f2bf(h);
      unsigned lo_u = f2bf(h - bf2f((unsigned short)hi_u));
      unsigned o_hi = (unsigned)__shfl_xor((int)hi_u, 1, 64);
      unsigned o_lo = (unsigned)__shfl_xor((int)lo_u, 1, 64);
      unsigned widx = pw + (unsigned)b * 512u + (unsigned)jp;
      if ((lr & 1) == 0) {
        hw[widx] = hi_u | (o_hi << 16);
      } else {
        hw[65536u + widx] = o_lo | (lo_u << 16);
      }
    }
  }
}

// ---------------------------------------------------------------------------
// Fallback step kernel (round-2 validated): used only if ws_size is too small.
// ---------------------------------------------------------------------------
__global__ __launch_bounds__(256) void rnn_step(const float* __restrict__ Wh,
                                                const float* __restrict__ bh,
                                                float* __restrict__ out,
                                                int t) {
  const int bg = blockIdx.x & 3;
  const int jg = blockIdx.x >> 2;
  const int b = bg * 16 + (threadIdx.x >> 4);
  const int j = jg * 16 + (threadIdx.x & 15);
  float a0 = 0.f, a1 = 0.f, a2 = 0.f, a3 = 0.f;
  if (t > 0) {
    const float4* __restrict__ wr = reinterpret_cast<const float4*>(&Wh[(long)j * H_]);
    const float4* __restrict__ hr = reinterpret_cast<const float4*>(
        &out[((long)b * T_ + (t - 1)) * H_]);
#pragma unroll 8
    for (int kc = 0; kc < 256; ++kc) {
      float4 w = wr[kc];
      float4 h = hr[kc];
      a0 = fmaf(w.x, h.x, a0);
      a1 = fmaf(w.y, h.y, a1);
      a2 = fmaf(w.z, h.z, a2);
      a3 = fmaf(w.w, h.w, a3);
    }
  }
  const long oi = ((long)b * T_ + t) * H_ + j;
  float z = out[oi] + ((a0 + a1) + (a2 + a3)) + bh[j];
  out[oi] = tanhf(z);
}

extern "C" void kernel_launch(void* const* d_in, const int* in_sizes, int n_in,
                              void* d_out, int out_size, void* d_ws, size_t ws_size,
                              hipStream_t stream) {
  const float* x  = (const float*)d_in[0];
  const float* Wi = (const float*)d_in[1];
  const float* bi = (const float*)d_in[2];
  const float* Wh = (const float*)d_in[3];
  const float* bh = (const float*)d_in[4];
  float* out = (float*)d_out;

  hipLaunchKernelGGL(xi_gemm, dim3(256, 8), dim3(256), 0, stream, x, Wi, bi, out);

  // ws: [0,256) ctr | hi[2][64][1024] ushort | lo[2][64][1024] ushort (512 KB)
  const size_t need = 256 + (size_t)4 * 64 * 1024 * sizeof(unsigned short);
  if (ws_size >= need) {
    unsigned* ctr = (unsigned*)d_ws;
    unsigned short* hs = (unsigned short*)((char*)d_ws + 256);
    hipMemsetAsync(d_ws, 0, 256, stream);  // reset barrier counter (capture-safe)
    const float* Wh_ = Wh; const float* bh_ = bh; float* out_ = out;
    void* args[] = {(void*)&Wh_, (void*)&bh_, (void*)&out_, (void*)&ctr, (void*)&hs};
    hipLaunchCooperativeKernel((void*)rnn_persist, dim3(NB), dim3(256),
                               args, 0, stream);
  } else {
    // deterministic fallback (validated round 2)
    for (int t = 0; t < T_; ++t)
      hipLaunchKernelGGL(rnn_step, dim3(256), dim3(256), 0, stream, Wh, bh, out, t);
  }
}

// Round 8
// 4468.624 us; speedup vs baseline: 4.4879x; 1.7664x over previous
//
#include <hip/hip_runtime.h>
#include <hip/hip_bf16.h>

#define B_ 64
#define T_ 512
#define D_ 1024
#define H_ 1024
#define NB 64  // persistent blocks: 1 per 16 output columns

typedef __bf16 bf16x8 __attribute__((ext_vector_type(8)));
typedef float f32x4 __attribute__((ext_vector_type(4)));

static __device__ __forceinline__ unsigned short f2bf(float f) {
  union { float f; unsigned u; } v; v.f = f;
  unsigned u = v.u;
  unsigned r = (u + 0x7fffu + ((u >> 16) & 1u)) >> 16;
  return (unsigned short)r;
}

// ---------------------------------------------------------------------------
// xi = x @ Wi^T + bi -> out[B,T,H]  (validated rounds 2/5/6/7)
// ---------------------------------------------------------------------------
__global__ __launch_bounds__(256) void xi_gemm(const float* __restrict__ x,
                                               const float* __restrict__ Wi,
                                               const float* __restrict__ bi,
                                               float* __restrict__ out) {
  __shared__ __align__(16) unsigned short As[128][40];
  __shared__ __align__(16) unsigned short Ws[128][40];
  const int tid = threadIdx.x;
  const int wave = tid >> 6;
  const int lane = tid & 63;
  const int wm = wave >> 1, wn = wave & 1;
  const int lr = lane & 15, lk = lane >> 4;
  const long row0 = (long)blockIdx.x * 128;
  const int col0 = (int)blockIdx.y * 128;

  f32x4 acc[4][4];
#pragma unroll
  for (int m = 0; m < 4; ++m)
#pragma unroll
    for (int n = 0; n < 4; ++n)
      acc[m][n] = (f32x4){0.f, 0.f, 0.f, 0.f};

  for (int kt = 0; kt < 32; ++kt) {
    __syncthreads();
#pragma unroll
    for (int it = 0; it < 4; ++it) {
      int i = tid + it * 256;
      int row = i >> 3, c = i & 7;
      float4 va = *reinterpret_cast<const float4*>(
          &x[(row0 + row) * 1024 + kt * 32 + c * 4]);
      ushort4 ba = {f2bf(va.x), f2bf(va.y), f2bf(va.z), f2bf(va.w)};
      *reinterpret_cast<ushort4*>(&As[row][c * 4]) = ba;
      float4 vw = *reinterpret_cast<const float4*>(
          &Wi[(long)(col0 + row) * 1024 + kt * 32 + c * 4]);
      ushort4 bw = {f2bf(vw.x), f2bf(vw.y), f2bf(vw.z), f2bf(vw.w)};
      *reinterpret_cast<ushort4*>(&Ws[row][c * 4]) = bw;
    }
    __syncthreads();
    bf16x8 af[4], wf[4];
#pragma unroll
    for (int m = 0; m < 4; ++m)
      af[m] = *reinterpret_cast<const bf16x8*>(&As[wm * 64 + m * 16 + lr][lk * 8]);
#pragma unroll
    for (int n = 0; n < 4; ++n)
      wf[n] = *reinterpret_cast<const bf16x8*>(&Ws[wn * 64 + n * 16 + lr][lk * 8]);
#pragma unroll
    for (int m = 0; m < 4; ++m)
#pragma unroll
      for (int n = 0; n < 4; ++n)
        acc[m][n] = __builtin_amdgcn_mfma_f32_16x16x32_bf16(af[m], wf[n], acc[m][n], 0, 0, 0);
  }
#pragma unroll
  for (int m = 0; m < 4; ++m) {
#pragma unroll
    for (int n = 0; n < 4; ++n) {
#pragma unroll
      for (int r = 0; r < 4; ++r) {
        long row = row0 + wm * 64 + m * 16 + lk * 4 + r;
        int col = col0 + wn * 64 + n * 16 + lr;
        out[row * 1024 + col] = acc[m][n][r] + bi[col];
      }
    }
  }
}

// ---------------------------------------------------------------------------
// Persistent recurrence v4: flag-array barrier (no RMW, no same-line spin)
// + sc1 h publication (nothing dirty -> no release fence) + acquire-inv only.
// Per step:
//   [all] packed-bf16 h stores via relaxed agent-scope u32 atomics (-> LLC)
//   __syncthreads            (vmcnt drained: stores complete at LLC)
//   wave0: lane0 stores t to OWN 64B-spaced flag slot (no RMW);
//          64 lanes poll the 64 slots (one vector load) until all >= t;
//          fence(acquire,"agent")  (buffer_inv: drop stale clean lines;
//                                   dirty out-lines survive)
//   __syncthreads; then wide CACHED h loads (L2 refill shared per XCD)
// h carried bf16-hi only (error budget: +~1e-3 over measured 0.0107, thr 0.02).
// ws: flags[64] @ 64B stride (4 KB) | h hi[2][64][1024] ushort (256 KB).
// ---------------------------------------------------------------------------
__global__ __launch_bounds__(256) void rnn_persist(const float* __restrict__ Wh,
                                                   const float* __restrict__ bh,
                                                   float* __restrict__ out,
                                                   unsigned* __restrict__ flags,
                                                   unsigned short* __restrict__ hs) {
  __shared__ __align__(16) unsigned short Whs[16][1032];  // +8 pad
  const int tid = threadIdx.x;
  const int wave = tid >> 6, lane = tid & 63;
  const int lr = lane & 15, lk = lane >> 4;
  const int j0 = blockIdx.x * 16;

  // stage Wh rows j0..j0+15 -> LDS bf16 (once)
#pragma unroll
  for (int it = 0; it < 16; ++it) {
    int i = tid + it * 256;      // 16 rows x 256 float4 chunks
    int row = i >> 8, c = i & 255;
    float4 v = *reinterpret_cast<const float4*>(&Wh[(long)(j0 + row) * 1024 + c * 4]);
    ushort4 b4 = {f2bf(v.x), f2bf(v.y), f2bf(v.z), f2bf(v.w)};
    *reinterpret_cast<ushort4*>(&Whs[row][c * 4]) = b4;
  }
  const float bhv = bh[j0 + lr];
  __syncthreads();

  const int brow = wave * 16;                    // this wave's batch-row tile
  const unsigned short* wbl = &Whs[lr][lk * 8];  // B-frag base (col j0+lr)
  unsigned* hw = reinterpret_cast<unsigned*>(hs);
  const int jp = (j0 >> 1) + (lr >> 1);          // col-pair index

  for (int t = 0; t < T_; ++t) {
    if (t > 0) {
      __syncthreads();  // all waves' sc1 h-stores drained (at LLC)
      if (tid < 64) {   // wave 0 runs the barrier
        if (tid == 0)
          __hip_atomic_store(&flags[(unsigned)blockIdx.x << 4], (unsigned)t,
                             __ATOMIC_RELAXED, __HIP_MEMORY_SCOPE_AGENT);
        unsigned spin = 0;
        for (;;) {
          unsigned v = __hip_atomic_load(&flags[(unsigned)tid << 4],
                                         __ATOMIC_RELAXED, __HIP_MEMORY_SCOPE_AGENT);
          if (__all((int)(v >= (unsigned)t))) break;
          __builtin_amdgcn_s_sleep(1);
          if (++spin > 50000u) break;  // fail loud, never wedge
        }
        __builtin_amdgcn_fence(__ATOMIC_ACQUIRE, "agent");  // buffer_inv
      }
      __syncthreads();  // other waves wait for inv before reading h
    }

    f32x4 a0 = {0, 0, 0, 0}, a1 = {0, 0, 0, 0};
    if (t > 0) {
      const size_t pb = (size_t)((t - 1) & 1) * 65536;   // parity base (ushort)
      const unsigned short* hbl = hs + pb + (size_t)(brow + lr) * 1024 + lk * 8;
      // 2 independent MFMA chains (two K-halves), 16 deep each; cached loads
#pragma unroll 4
      for (int ks = 0; ks < 16; ++ks) {
        bf16x8 ah0 = *reinterpret_cast<const bf16x8*>(hbl + ks * 32);
        bf16x8 ah1 = *reinterpret_cast<const bf16x8*>(hbl + (ks + 16) * 32);
        bf16x8 wf0 = *reinterpret_cast<const bf16x8*>(wbl + ks * 32);
        bf16x8 wf1 = *reinterpret_cast<const bf16x8*>(wbl + (ks + 16) * 32);
        a0 = __builtin_amdgcn_mfma_f32_16x16x32_bf16(ah0, wf0, a0, 0, 0, 0);
        a1 = __builtin_amdgcn_mfma_f32_16x16x32_bf16(ah1, wf1, a1, 0, 0, 0);
      }
    }
    f32x4 acc = a0 + a1;

    // epilogue: lane owns col j0+lr, rows brow + lk*4 + r (m89 D-layout).
    // Lane pairs exchange via shfl; even lane publishes packed hi col-pair
    // as a relaxed agent-scope u32 store (write-through to LLC).
    const unsigned pw = (unsigned)(t & 1) * 32768u;      // parity base (u32)
    const int jcol = j0 + lr;
#pragma unroll
    for (int r = 0; r < 4; ++r) {
      int b = brow + lk * 4 + r;
      size_t oi = ((size_t)b * T_ + t) * H_ + jcol;
      float z = out[oi] + acc[r] + bhv;
      float h = tanhf(z);
      out[oi] = h;
      unsigned hi_u = f2bf(h);
      unsigned o_hi = (unsigned)__shfl_xor((int)hi_u, 1, 64);
      if ((lr & 1) == 0) {
        __hip_atomic_store(&hw[pw + (unsigned)b * 512u + (unsigned)jp],
                           hi_u | (o_hi << 16),
                           __ATOMIC_RELAXED, __HIP_MEMORY_SCOPE_AGENT);
      }
    }
  }
}

// ---------------------------------------------------------------------------
// Fallback step kernel (round-2 validated): used only if ws_size is too small.
// ---------------------------------------------------------------------------
__global__ __launch_bounds__(256) void rnn_step(const float* __restrict__ Wh,
                                                const float* __restrict__ bh,
                                                float* __restrict__ out,
                                                int t) {
  const int bg = blockIdx.x & 3;
  const int jg = blockIdx.x >> 2;
  const int b = bg * 16 + (threadIdx.x >> 4);
  const int j = jg * 16 + (threadIdx.x & 15);
  float a0 = 0.f, a1 = 0.f, a2 = 0.f, a3 = 0.f;
  if (t > 0) {
    const float4* __restrict__ wr = reinterpret_cast<const float4*>(&Wh[(long)j * H_]);
    const float4* __restrict__ hr = reinterpret_cast<const float4*>(
        &out[((long)b * T_ + (t - 1)) * H_]);
#pragma unroll 8
    for (int kc = 0; kc < 256; ++kc) {
      float4 w = wr[kc];
      float4 h = hr[kc];
      a0 = fmaf(w.x, h.x, a0);
      a1 = fmaf(w.y, h.y, a1);
      a2 = fmaf(w.z, h.z, a2);
      a3 = fmaf(w.w, h.w, a3);
    }
  }
  const long oi = ((long)b * T_ + t) * H_ + j;
  float z = out[oi] + ((a0 + a1) + (a2 + a3)) + bh[j];
  out[oi] = tanhf(z);
}

extern "C" void kernel_launch(void* const* d_in, const int* in_sizes, int n_in,
                              void* d_out, int out_size, void* d_ws, size_t ws_size,
                              hipStream_t stream) {
  const float* x  = (const float*)d_in[0];
  const float* Wi = (const float*)d_in[1];
  const float* bi = (const float*)d_in[2];
  const float* Wh = (const float*)d_in[3];
  const float* bh = (const float*)d_in[4];
  float* out = (float*)d_out;

  hipLaunchKernelGGL(xi_gemm, dim3(256, 8), dim3(256), 0, stream, x, Wi, bi, out);

  // ws: flags 64 x 64B (4 KB) | h hi[2][64][1024] ushort (256 KB)
  const size_t need = 4096 + (size_t)2 * 64 * 1024 * sizeof(unsigned short);
  if (ws_size >= need) {
    unsigned* flags = (unsigned*)d_ws;
    unsigned short* hs = (unsigned short*)((char*)d_ws + 4096);
    hipMemsetAsync(d_ws, 0, 4096, stream);  // reset flags (capture-safe, replayed)
    const float* Wh_ = Wh; const float* bh_ = bh; float* out_ = out;
    void* args[] = {(void*)&Wh_, (void*)&bh_, (void*)&out_, (void*)&flags, (void*)&hs};
    hipLaunchCooperativeKernel((void*)rnn_persist, dim3(NB), dim3(256),
                               args, 0, stream);
  } else {
    // deterministic fallback (validated round 2)
    for (int t = 0; t < T_; ++t)
      hipLaunchKernelGGL(rnn_step, dim3(256), dim3(256), 0, stream, Wh, bh, out, t);
  }
}